// Round 18
// baseline (56.167 us; speedup 1.0000x reference)
//
#include <hip/hip_runtime.h>
#include <hip/hip_bf16.h>

#define NPER 24
#define B_ 32
#define N_ 1024
#define F_ 128
#define H_ 64
#define E_ 16

typedef __attribute__((ext_vector_type(8))) short short8;
typedef __attribute__((ext_vector_type(4))) float f32x4;

#define GLD16(g, l) __builtin_amdgcn_global_load_lds( \
    (const __attribute__((address_space(1))) void*)(g), \
    (__attribute__((address_space(3))) void*)(l), 16, 0, 0)

static __device__ __forceinline__ unsigned short f2bf(float x) {
    union { float f; unsigned u; } v; v.f = x;
    unsigned r = v.u + 0x7fffu + ((v.u >> 16) & 1u);   // RNE
    return (unsigned short)(r >> 16);
}
static __device__ __forceinline__ float bf2f(unsigned short h) {
    union { unsigned u; float f; } v; v.u = ((unsigned)h) << 16; return v.f;
}
static __device__ __forceinline__ unsigned short f2bf_hw(float x) {
    __hip_bfloat16 h = __float2bfloat16(x);
    return *(unsigned short*)&h;
}

// ---------------------------------------------------------------------------
// P1: all prep in one launch.  [r17-verified, unchanged]
// ---------------------------------------------------------------------------
__global__ __launch_bounds__(256) void prep_all(
    const float* __restrict__ src_emb, const float* __restrict__ tgt_emb,
    const float* __restrict__ env_features, const float* __restrict__ env_W,
    const float* __restrict__ env_b,
    const float* __restrict__ adj, const float* __restrict__ W,
    const float* __restrict__ rW, const float* __restrict__ x,
    unsigned short* __restrict__ src_bf, unsigned short* __restrict__ tgt_bf,
    unsigned short* __restrict__ adj_bf, unsigned short* __restrict__ Wt,
    unsigned short* __restrict__ rWt, unsigned short* __restrict__ x_bf)
{
    const int bid = blockIdx.x;
    if (bid < 1536) {
        const int g   = bid >> 8;                          // p-group 0..5
        const int idx = (bid & 255) * 256 + threadIdx.x;   // 0..65535
        const int n = idx >> 6, h = idx & 63;
        float e = env_b[h];
#pragma unroll
        for (int k = 0; k < E_; ++k)
            e = fmaf(env_features[n * E_ + k], env_W[k * H_ + h], e);
        e = fmaxf(e, 0.f);
#pragma unroll
        for (int pp = 0; pp < 4; ++pp) {
            const size_t off = (size_t)(g * 4 + pp) * (N_ * H_) + idx;
            src_bf[off] = f2bf(src_emb[off] + e);
            tgt_bf[off] = f2bf(tgt_emb[off] + e);
        }
    } else if (bid < 2560) {
        const size_t i = ((size_t)(bid - 1536) * 256 + threadIdx.x) * 4;
        float4 v = *(const float4*)(adj + i);
        ushort4 o;
        o.x = f2bf(v.x); o.y = f2bf(v.y); o.z = f2bf(v.z); o.w = f2bf(v.w);
        *(ushort4*)(adj_bf + i) = o;
    } else if (bid < 2688) {
        const int idx = (bid - 2560) * 256 + threadIdx.x;   // 0..32767
        const int which = idx >> 14, j = idx & 16383;
        const int f = j >> 7, d = j & 127;
        if (which == 0) Wt[f * 128 + d]  = f2bf(W[d * 128 + f]);
        else            rWt[f * 128 + d] = f2bf(rW[d * 128 + f]);
    } else {
        const size_t i = ((size_t)(bid - 2688) * 256 + threadIdx.x) * 4;
        float4 v = *(const float4*)(x + i);
        ushort4 o;
        o.x = f2bf(v.x); o.y = f2bf(v.y); o.z = f2bf(v.z); o.w = f2bf(v.w);
        *(ushort4*)(x_bf + i) = o;
    }
}

// ---------------------------------------------------------------------------
// K5: support^T + residual, LDS-staged. [r17-verified, unchanged]
// ---------------------------------------------------------------------------
__global__ __launch_bounds__(256, 2) void gemm2_mfma(
    const unsigned short* __restrict__ x_bf,   // [B*N][128]
    const unsigned short* __restrict__ Wt,     // [128f][128d]
    const unsigned short* __restrict__ rWt,    // [128f][128d]
    const float* __restrict__ rb,              // [128]
    unsigned short* __restrict__ supT,         // [B][128f][1024m]
    unsigned short* __restrict__ resid)        // [B*N][128]
{
    __shared__ unsigned short s_w[128 * 128] __attribute__((aligned(16)));
    __shared__ unsigned short s_r[128 * 128] __attribute__((aligned(16)));
    __shared__ unsigned short s_x[64 * 128]  __attribute__((aligned(16)));

    const int t = threadIdx.x, w = t >> 6, l = t & 63;
    const int ln = l & 15, kb = l >> 4;
    const size_t row0 = (size_t)blockIdx.x * 64;
    const int b   = (int)(row0 >> 10);
    const int mg0 = (int)(row0 & 1023);

#pragma unroll
    for (int j = 0; j < 8; ++j) {
        const int te = j * 256 + t;
        const int r = te >> 4, c = te & 15;
        GLD16(Wt  + (size_t)r * 128 + (c ^ (r & 7)) * 8, &s_w[te * 8]);
        GLD16(rWt + (size_t)r * 128 + (c ^ (r & 7)) * 8, &s_r[te * 8]);
    }
#pragma unroll
    for (int j = 0; j < 4; ++j) {
        const int te = j * 256 + t;
        const int r = te >> 4, c = te & 15;
        GLD16(x_bf + row0 * 128 + (size_t)r * 128 + (c ^ (r & 7)) * 8,
              &s_x[te * 8]);
    }
    asm volatile("s_waitcnt vmcnt(0) lgkmcnt(0)" ::: "memory");
    __builtin_amdgcn_s_barrier();

    f32x4 accS[8], accR[8];
#pragma unroll
    for (int q = 0; q < 8; ++q) { accS[q] = (f32x4){0,0,0,0}; accR[q] = (f32x4){0,0,0,0}; }

    const int xr = w * 16 + ln;
#pragma unroll
    for (int k = 0; k < 4; ++k) {
        short8 xa = *(const short8*)(&s_x[xr * 128 + ((k * 4 + kb) ^ (xr & 7)) * 8]);
#pragma unroll
        for (int ff = 0; ff < 8; ++ff) {
            const int fr = ff * 16 + ln;
            short8 wa = *(const short8*)(&s_w[fr * 128 + ((k * 4 + kb) ^ (fr & 7)) * 8]);
            short8 wb = *(const short8*)(&s_r[fr * 128 + ((k * 4 + kb) ^ (fr & 7)) * 8]);
            accS[ff] = __builtin_amdgcn_mfma_f32_16x16x32_bf16(wa, xa, accS[ff], 0, 0, 0);
            accR[ff] = __builtin_amdgcn_mfma_f32_16x16x32_bf16(xa, wb, accR[ff], 0, 0, 0);
        }
    }

#pragma unroll
    for (int ff = 0; ff < 8; ++ff) {
        const int m = mg0 + w * 16 + ln;
#pragma unroll
        for (int i = 0; i < 4; ++i) {
            const int f = ff * 16 + kb * 4 + i;
            supT[((size_t)b * 128 + f) * 1024 + m] = f2bf(accS[ff][i]);
        }
    }
#pragma unroll
    for (int ff = 0; ff < 8; ++ff) {
        const int f = ff * 16 + ln;
        const float rbf = rb[f];
#pragma unroll
        for (int i = 0; i < 4; ++i) {
            const size_t row = row0 + w * 16 + kb * 4 + i;
            resid[row * 128 + f] = f2bf(fmaxf(accR[ff][i] + rbf, 0.f));
        }
    }
}

// ---------------------------------------------------------------------------
// K6: depth-2 pipelined conv. Block = (b, 64n), grid 512 XCD-swizzled,
// 4 waves, 32-m chunks (32 total), 4 LDS buffers (~52 KB -> 3 blocks/CU).
// Per chunk c: issue stage(c+2) -> counted vmcnt(10) retires chunk c
// (issued 2 chunks of compute earlier) -> barrier -> score -> bar_lgkm ->
// conv. 2 barriers/chunk, no vmcnt(0) until the tail. Loop unrolled x4 for
// static buffer/av indices (rule #20); explicit tail vmcnt 10/10/5/0.
// Score roles: sn=w>>1 (32n half), sm=w&1 (16m half). Conv: cf=w (32 f).
// VMEM/thread/chunk = 1 tgt GLD16 + 2 sup GLD16 + 2 adj dwordx2 = 5.
// ---------------------------------------------------------------------------
__global__ __launch_bounds__(256, 3) void conv_mfma(
    const unsigned short* __restrict__ src_bf,  // [P][N][64]
    const unsigned short* __restrict__ tgt_bf,  // [P][N][64]
    const unsigned short* __restrict__ adj_bf,  // [N][N]
    const unsigned short* __restrict__ supT,    // [B][128][1024]
    const unsigned short* __restrict__ resid,   // [B*N][128]
    const float* __restrict__ bias,             // [128]
    const int* __restrict__ cyc,                // [B]
    float* __restrict__ out)                    // [B][N][128]
{
    __shared__ unsigned short s_tgt[4][32 * 64]  __attribute__((aligned(16))); // 16KB
    __shared__ unsigned short s_sup[4][128 * 32] __attribute__((aligned(16))); // 32KB
    __shared__ unsigned short s_a[64][36]        __attribute__((aligned(16))); // 4.5KB

    const int i = blockIdx.x;                    // 0..511
    const int work = (i & 7) * 64 + (i >> 3);    // XCD k: 2 consecutive b's
    const int b  = work >> 4;
    const int n0 = (work & 15) * 64;

    const int t = threadIdx.x, w = t >> 6, l = t & 63;
    const int ln = l & 15, kb = l >> 4;
    const int p = ((cyc[b] % NPER) + NPER) % NPER;

    const int sn = w >> 1, sm = w & 1;   // score: 32n-half x 16m-half
    const int cf = w;                    // conv: 32 f columns per wave

    // src fragments (score B-operand): col n = ln  [r10-verified layout]
    short8 sfrag[2][2];
#pragma unroll
    for (int nt = 0; nt < 2; ++nt)
#pragma unroll
        for (int k2 = 0; k2 < 2; ++k2)
            sfrag[nt][k2] = *(const short8*)(
                src_bf + ((size_t)p * N_ + n0 + sn * 32 + nt * 16 + ln) * H_ + k2 * 32 + kb * 8);

    const unsigned short* tgtg = tgt_bf + (size_t)p * N_ * H_;
    const unsigned short* supg = supT + (size_t)b * F_ * N_;

    f32x4 acc[4][2];
#pragma unroll
    for (int q = 0; q < 4; ++q)
#pragma unroll
        for (int fb = 0; fb < 2; ++fb) acc[q][fb] = (f32x4){0, 0, 0, 0};

    // 3 GLD16/thread per chunk; src pre-swizzled (rule #21)
    auto stage = [&](int buf, int m0) {
        {   // tgt: 32 m-rows x 8 chunks(16B); swizzle c^(r&7)
            const int r = t >> 3, c = t & 7;
            GLD16(tgtg + (size_t)(m0 + r) * H_ + (c ^ (r & 7)) * 8,
                  &s_tgt[buf][t * 8]);
        }
#pragma unroll
        for (int j = 0; j < 2; ++j) {   // sup: 128 f-rows x 4 chunks; c^((r>>1)&3)
            const int te = j * 256 + t;
            const int r = te >> 2, c = te & 3;
            GLD16(supg + (size_t)r * N_ + m0 + (c ^ ((r >> 1) & 3)) * 8,
                  &s_sup[buf][te * 8]);
        }
    };

    // 2 VMEM/thread per chunk
    auto loadAdj = [&](int m0, ushort4 (&av)[2]) {
#pragma unroll
        for (int nt = 0; nt < 2; ++nt)
            av[nt] = *(const ushort4*)(
                adj_bf + (size_t)(n0 + sn * 32 + nt * 16 + ln) * N_
                       + m0 + sm * 16 + kb * 4);
    };

    auto score = [&](int buf, const ushort4 (&av)[2]) {
        const int trow = sm * 16 + ln;           // m-row within 32-m chunk
        short8 tf0 = *(const short8*)(
            &s_tgt[buf][trow * 64 + ((kb) ^ (trow & 7)) * 8]);
        short8 tf1 = *(const short8*)(
            &s_tgt[buf][trow * 64 + ((4 + kb) ^ (trow & 7)) * 8]);
#pragma unroll
        for (int nt = 0; nt < 2; ++nt) {
            f32x4 c = (f32x4){0, 0, 0, 0};
            c = __builtin_amdgcn_mfma_f32_16x16x32_bf16(tf0, sfrag[nt][0], c, 0, 0, 0);
            c = __builtin_amdgcn_mfma_f32_16x16x32_bf16(tf1, sfrag[nt][1], c, 0, 0, 0);
            // lane: score[m = sm*16+kb*4+i][n = sn*32+nt*16+ln]  [verified]
            const int nl = sn * 32 + nt * 16 + ln;
            const int ml = sm * 16 + kb * 4;
            const ushort4 a = av[nt];
            uint2 q;
            q.x = (unsigned)f2bf_hw(fmaxf(c[0], 0.f) * bf2f(a.x))
                | ((unsigned)f2bf_hw(fmaxf(c[1], 0.f) * bf2f(a.y)) << 16);
            q.y = (unsigned)f2bf_hw(fmaxf(c[2], 0.f) * bf2f(a.z))
                | ((unsigned)f2bf_hw(fmaxf(c[3], 0.f) * bf2f(a.w)) << 16);
            *(uint2*)(&s_a[nl][ml]) = q;
        }
    };

    auto conv = [&](int buf) {
        short8 bfrag[2];
#pragma unroll
        for (int fb = 0; fb < 2; ++fb) {
            const int frow = cf * 32 + fb * 16 + ln;
            bfrag[fb] = *(const short8*)(
                &s_sup[buf][frow * 32 + ((kb) ^ ((frow >> 1) & 3)) * 8]);
        }
#pragma unroll
        for (int nt2 = 0; nt2 < 4; ++nt2) {
            short8 af = *(const short8*)(&s_a[nt2 * 16 + ln][kb * 8]);
#pragma unroll
            for (int fb = 0; fb < 2; ++fb)
                acc[nt2][fb] = __builtin_amdgcn_mfma_f32_16x16x32_bf16(
                    af, bfrag[fb], acc[nt2][fb], 0, 0, 0);
        }
    };

    auto bar = []() { __builtin_amdgcn_s_barrier(); };
    auto bar_lgkm = []() {
        asm volatile("s_waitcnt lgkmcnt(0)" ::: "memory");
        __builtin_amdgcn_s_barrier();
    };

    ushort4 av[4][2];

    // prologue: chunks 0,1 in flight (10 VMEM)
    stage(0, 0);        loadAdj(0, av[0]);
    stage(1, 32);       loadAdj(32, av[1]);

    // main loop: chunks 0..27, unrolled x4 (static buf/av indices)
#pragma unroll 1
    for (int k = 0; k < 7; ++k) {
        const int c0 = k * 4;
#pragma unroll
        for (int u = 0; u < 4; ++u) {
            const int c = c0 + u;
            stage((u + 2) & 3, (c + 2) * 32);
            loadAdj((c + 2) * 32, av[(u + 2) & 3]);
            __builtin_amdgcn_sched_barrier(0);
            asm volatile("s_waitcnt vmcnt(10)" ::: "memory");  // chunk c landed
            bar();
            score(u & 3, av[u & 3]);
            bar_lgkm();
            conv(u & 3);
        }
    }
    // tail: chunks 28..31
    {
        stage(2, 30 * 32);  loadAdj(30 * 32, av[2]);
        __builtin_amdgcn_sched_barrier(0);
        asm volatile("s_waitcnt vmcnt(10)" ::: "memory");
        bar(); score(0, av[0]); bar_lgkm(); conv(0);

        stage(3, 31 * 32);  loadAdj(31 * 32, av[3]);
        __builtin_amdgcn_sched_barrier(0);
        asm volatile("s_waitcnt vmcnt(10)" ::: "memory");
        bar(); score(1, av[1]); bar_lgkm(); conv(1);

        asm volatile("s_waitcnt vmcnt(5)" ::: "memory");
        bar(); score(2, av[2]); bar_lgkm(); conv(2);

        asm volatile("s_waitcnt vmcnt(0)" ::: "memory");
        bar(); score(3, av[3]); bar_lgkm(); conv(3);
    }

    // epilogue: out = relu(conv + bias + residual)
#pragma unroll
    for (int nt2 = 0; nt2 < 4; ++nt2)
#pragma unroll
    for (int fb = 0; fb < 2; ++fb) {
        const int f = cf * 32 + fb * 16 + ln;
        const float bi = bias[f];
#pragma unroll
        for (int ii = 0; ii < 4; ++ii) {
            const int n = n0 + nt2 * 16 + kb * 4 + ii;
            const size_t o = ((size_t)b * N_ + n) * F_ + f;
            out[o] = fmaxf(acc[nt2][fb][ii] + bi + bf2f(resid[o]), 0.f);
        }
    }
}

// ---------------------------------------------------------------------------
extern "C" void kernel_launch(void* const* d_in, const int* in_sizes, int n_in,
                              void* d_out, int out_size, void* d_ws, size_t ws_size,
                              hipStream_t stream) {
    const float* input_features = (const float*)d_in[0];
    const int*   cycle_indices  = (const int*)  d_in[1];
    const float* weight         = (const float*)d_in[2];
    const float* bias           = (const float*)d_in[3];
    const float* src_emb        = (const float*)d_in[4];
    const float* tgt_emb        = (const float*)d_in[5];
    const float* env_W          = (const float*)d_in[6];
    const float* env_b          = (const float*)d_in[7];
    const float* res_W          = (const float*)d_in[8];
    const float* res_b          = (const float*)d_in[9];
    const float* static_adj     = (const float*)d_in[10];
    const float* env_features   = (const float*)d_in[11];
    float* out = (float*)d_out;

    // workspace layout (~33.6 MiB)
    char* wsb = (char*)d_ws;
    unsigned short* src_bf = (unsigned short*)wsb;               // 3145728 B
    unsigned short* tgt_bf = src_bf + (size_t)NPER * N_ * H_;    // 3145728 B
    unsigned short* Wt     = tgt_bf + (size_t)NPER * N_ * H_;    // 32768 B
    unsigned short* rWt    = Wt + 16384;                         // 32768 B
    unsigned short* supT   = rWt + 16384;                        // 8388608 B
    unsigned short* resid  = supT + (size_t)B_ * F_ * N_;        // 8388608 B
    unsigned short* adj_bf = resid + (size_t)B_ * N_ * F_;       // 2097152 B
    unsigned short* x_bf   = adj_bf + (size_t)N_ * N_;           // 8388608 B

    prep_all<<<6784, 256, 0, stream>>>(
        src_emb, tgt_emb, env_features, env_W, env_b,
        static_adj, weight, res_W, input_features,
        src_bf, tgt_bf, adj_bf, Wt, rWt, x_bf);

    gemm2_mfma<<<(B_ * N_) / 64, 256, 0, stream>>>(
        x_bf, Wt, rWt, res_b, supT, resid);

    conv_mfma<<<512, 256, 0, stream>>>(
        src_bf, tgt_bf, adj_bf, supT, resid, bias, cycle_indices, out);
}

// Round 19
// 54.884 us; speedup vs baseline: 1.0234x; 1.0234x over previous
//
#include <hip/hip_runtime.h>
#include <hip/hip_bf16.h>

#define NPER 24
#define B_ 32
#define N_ 1024
#define F_ 128
#define H_ 64
#define E_ 16

typedef __attribute__((ext_vector_type(8))) short short8;
typedef __attribute__((ext_vector_type(4))) float f32x4;

#define GLD16(g, l) __builtin_amdgcn_global_load_lds( \
    (const __attribute__((address_space(1))) void*)(g), \
    (__attribute__((address_space(3))) void*)(l), 16, 0, 0)

static __device__ __forceinline__ unsigned short f2bf(float x) {
    union { float f; unsigned u; } v; v.f = x;
    unsigned r = v.u + 0x7fffu + ((v.u >> 16) & 1u);   // RNE
    return (unsigned short)(r >> 16);
}
static __device__ __forceinline__ float bf2f(unsigned short h) {
    union { unsigned u; float f; } v; v.u = ((unsigned)h) << 16; return v.f;
}
static __device__ __forceinline__ unsigned short f2bf_hw(float x) {
    __hip_bfloat16 h = __float2bfloat16(x);
    return *(unsigned short*)&h;
}

// ---------------------------------------------------------------------------
// P1: all prep in one launch.  [r17-verified best]
// ---------------------------------------------------------------------------
__global__ __launch_bounds__(256) void prep_all(
    const float* __restrict__ src_emb, const float* __restrict__ tgt_emb,
    const float* __restrict__ env_features, const float* __restrict__ env_W,
    const float* __restrict__ env_b,
    const float* __restrict__ adj, const float* __restrict__ W,
    const float* __restrict__ rW, const float* __restrict__ x,
    unsigned short* __restrict__ src_bf, unsigned short* __restrict__ tgt_bf,
    unsigned short* __restrict__ adj_bf, unsigned short* __restrict__ Wt,
    unsigned short* __restrict__ rWt, unsigned short* __restrict__ x_bf)
{
    const int bid = blockIdx.x;
    if (bid < 1536) {
        const int g   = bid >> 8;                          // p-group 0..5
        const int idx = (bid & 255) * 256 + threadIdx.x;   // 0..65535
        const int n = idx >> 6, h = idx & 63;
        float e = env_b[h];
#pragma unroll
        for (int k = 0; k < E_; ++k)
            e = fmaf(env_features[n * E_ + k], env_W[k * H_ + h], e);
        e = fmaxf(e, 0.f);
#pragma unroll
        for (int pp = 0; pp < 4; ++pp) {
            const size_t off = (size_t)(g * 4 + pp) * (N_ * H_) + idx;
            src_bf[off] = f2bf(src_emb[off] + e);
            tgt_bf[off] = f2bf(tgt_emb[off] + e);
        }
    } else if (bid < 2560) {
        const size_t i = ((size_t)(bid - 1536) * 256 + threadIdx.x) * 4;
        float4 v = *(const float4*)(adj + i);
        ushort4 o;
        o.x = f2bf(v.x); o.y = f2bf(v.y); o.z = f2bf(v.z); o.w = f2bf(v.w);
        *(ushort4*)(adj_bf + i) = o;
    } else if (bid < 2688) {
        const int idx = (bid - 2560) * 256 + threadIdx.x;   // 0..32767
        const int which = idx >> 14, j = idx & 16383;
        const int f = j >> 7, d = j & 127;
        if (which == 0) Wt[f * 128 + d]  = f2bf(W[d * 128 + f]);
        else            rWt[f * 128 + d] = f2bf(rW[d * 128 + f]);
    } else {
        const size_t i = ((size_t)(bid - 2688) * 256 + threadIdx.x) * 4;
        float4 v = *(const float4*)(x + i);
        ushort4 o;
        o.x = f2bf(v.x); o.y = f2bf(v.y); o.z = f2bf(v.z); o.w = f2bf(v.w);
        *(ushort4*)(x_bf + i) = o;
    }
}

// ---------------------------------------------------------------------------
// K5: support^T + residual, LDS-staged. [r17-verified best]
// ---------------------------------------------------------------------------
__global__ __launch_bounds__(256, 2) void gemm2_mfma(
    const unsigned short* __restrict__ x_bf,   // [B*N][128]
    const unsigned short* __restrict__ Wt,     // [128f][128d]
    const unsigned short* __restrict__ rWt,    // [128f][128d]
    const float* __restrict__ rb,              // [128]
    unsigned short* __restrict__ supT,         // [B][128f][1024m]
    unsigned short* __restrict__ resid)        // [B*N][128]
{
    __shared__ unsigned short s_w[128 * 128] __attribute__((aligned(16)));
    __shared__ unsigned short s_r[128 * 128] __attribute__((aligned(16)));
    __shared__ unsigned short s_x[64 * 128]  __attribute__((aligned(16)));

    const int t = threadIdx.x, w = t >> 6, l = t & 63;
    const int ln = l & 15, kb = l >> 4;
    const size_t row0 = (size_t)blockIdx.x * 64;
    const int b   = (int)(row0 >> 10);
    const int mg0 = (int)(row0 & 1023);

#pragma unroll
    for (int j = 0; j < 8; ++j) {
        const int te = j * 256 + t;
        const int r = te >> 4, c = te & 15;
        GLD16(Wt  + (size_t)r * 128 + (c ^ (r & 7)) * 8, &s_w[te * 8]);
        GLD16(rWt + (size_t)r * 128 + (c ^ (r & 7)) * 8, &s_r[te * 8]);
    }
#pragma unroll
    for (int j = 0; j < 4; ++j) {
        const int te = j * 256 + t;
        const int r = te >> 4, c = te & 15;
        GLD16(x_bf + row0 * 128 + (size_t)r * 128 + (c ^ (r & 7)) * 8,
              &s_x[te * 8]);
    }
    asm volatile("s_waitcnt vmcnt(0) lgkmcnt(0)" ::: "memory");
    __builtin_amdgcn_s_barrier();

    f32x4 accS[8], accR[8];
#pragma unroll
    for (int q = 0; q < 8; ++q) { accS[q] = (f32x4){0,0,0,0}; accR[q] = (f32x4){0,0,0,0}; }

    const int xr = w * 16 + ln;
#pragma unroll
    for (int k = 0; k < 4; ++k) {
        short8 xa = *(const short8*)(&s_x[xr * 128 + ((k * 4 + kb) ^ (xr & 7)) * 8]);
#pragma unroll
        for (int ff = 0; ff < 8; ++ff) {
            const int fr = ff * 16 + ln;
            short8 wa = *(const short8*)(&s_w[fr * 128 + ((k * 4 + kb) ^ (fr & 7)) * 8]);
            short8 wb = *(const short8*)(&s_r[fr * 128 + ((k * 4 + kb) ^ (fr & 7)) * 8]);
            accS[ff] = __builtin_amdgcn_mfma_f32_16x16x32_bf16(wa, xa, accS[ff], 0, 0, 0);
            accR[ff] = __builtin_amdgcn_mfma_f32_16x16x32_bf16(xa, wb, accR[ff], 0, 0, 0);
        }
    }

#pragma unroll
    for (int ff = 0; ff < 8; ++ff) {
        const int m = mg0 + w * 16 + ln;
#pragma unroll
        for (int i = 0; i < 4; ++i) {
            const int f = ff * 16 + kb * 4 + i;
            supT[((size_t)b * 128 + f) * 1024 + m] = f2bf(accS[ff][i]);
        }
    }
#pragma unroll
    for (int ff = 0; ff < 8; ++ff) {
        const int f = ff * 16 + ln;
        const float rbf = rb[f];
#pragma unroll
        for (int i = 0; i < 4; ++i) {
            const size_t row = row0 + w * 16 + kb * 4 + i;
            resid[row * 128 + f] = f2bf(fmaxf(accR[ff][i] + rbf, 0.f));
        }
    }
}

// ---------------------------------------------------------------------------
// K6: r10-EXACT fused conv (best measured structure).
// ---------------------------------------------------------------------------
__global__ __launch_bounds__(256, 2) void conv_mfma(
    const unsigned short* __restrict__ src_bf,  // [P][N][64]
    const unsigned short* __restrict__ tgt_bf,  // [P][N][64]
    const unsigned short* __restrict__ adj_bf,  // [N][N]
    const unsigned short* __restrict__ supT,    // [B][128][1024]
    const unsigned short* __restrict__ resid,   // [B*N][128]
    const float* __restrict__ bias,             // [128]
    const int* __restrict__ cyc,                // [B]
    float* __restrict__ out)                    // [B][N][128]
{
    __shared__ unsigned short s_tgt[2][64 * 64] __attribute__((aligned(16)));
    __shared__ unsigned short s_sup[2][128 * 64] __attribute__((aligned(16)));
    __shared__ unsigned short s_a[64][72] __attribute__((aligned(16)));

    const int i = blockIdx.x;                    // 0..511
    const int work = (i & 7) * 64 + (i >> 3);    // XCD k: 2 consecutive b's
    const int b  = work >> 4;
    const int n0 = (work & 15) * 64;

    const int t = threadIdx.x, w = t >> 6, l = t & 63;
    const int ln = l & 15, kb = l >> 4;
    const int p = ((cyc[b] % NPER) + NPER) % NPER;

    const int sn = w >> 1, sm = w & 1;   // score: 32n x 32m quarter per wave
    const int cf = w;                    // conv: 32 f columns per wave

    short8 sfrag[2][2];
#pragma unroll
    for (int nt = 0; nt < 2; ++nt)
#pragma unroll
        for (int k2 = 0; k2 < 2; ++k2)
            sfrag[nt][k2] = *(const short8*)(
                src_bf + ((size_t)p * N_ + n0 + sn * 32 + nt * 16 + ln) * H_ + k2 * 32 + kb * 8);

    const unsigned short* tgtg = tgt_bf + (size_t)p * N_ * H_;
    const unsigned short* supg = supT + (size_t)b * F_ * N_;

    f32x4 acc[4][2];
#pragma unroll
    for (int q = 0; q < 4; ++q)
#pragma unroll
        for (int fb = 0; fb < 2; ++fb) acc[q][fb] = (f32x4){0, 0, 0, 0};

    auto stage = [&](int buf, int m0) {
#pragma unroll
        for (int j = 0; j < 2; ++j) {
            const int te = j * 256 + t;
            const int r = te >> 3, c = te & 7;
            GLD16(tgtg + (size_t)(m0 + r) * H_ + (c ^ (r & 7)) * 8,
                  &s_tgt[buf][te * 8]);
        }
#pragma unroll
        for (int j = 0; j < 4; ++j) {
            const int te = j * 256 + t;
            const int r = te >> 3, c = te & 7;
            GLD16(supg + (size_t)r * N_ + m0 + (c ^ (r & 7)) * 8,
                  &s_sup[buf][te * 8]);
        }
    };

    auto loadAdj = [&](int m0, ushort4 (&av)[2][2]) {
#pragma unroll
        for (int nt = 0; nt < 2; ++nt)
#pragma unroll
            for (int mt = 0; mt < 2; ++mt)
                av[nt][mt] = *(const ushort4*)(
                    adj_bf + (size_t)(n0 + sn * 32 + nt * 16 + ln) * N_
                           + m0 + sm * 32 + mt * 16 + kb * 4);
    };

    auto score = [&](int buf, const ushort4 (&av)[2][2]) {
        short8 tf[2][2];
#pragma unroll
        for (int mt = 0; mt < 2; ++mt)
#pragma unroll
            for (int k2 = 0; k2 < 2; ++k2) {
                const int trow = sm * 32 + mt * 16 + ln;
                tf[mt][k2] = *(const short8*)(
                    &s_tgt[buf][trow * 64 + ((k2 * 4 + kb) ^ (trow & 7)) * 8]);
            }
#pragma unroll
        for (int nt = 0; nt < 2; ++nt)
#pragma unroll
            for (int mt = 0; mt < 2; ++mt) {
                f32x4 c = (f32x4){0, 0, 0, 0};
                c = __builtin_amdgcn_mfma_f32_16x16x32_bf16(tf[mt][0], sfrag[nt][0], c, 0, 0, 0);
                c = __builtin_amdgcn_mfma_f32_16x16x32_bf16(tf[mt][1], sfrag[nt][1], c, 0, 0, 0);
                const int nl = sn * 32 + nt * 16 + ln;
                const int ml = sm * 32 + mt * 16 + kb * 4;
                const ushort4 a = av[nt][mt];
                uint2 q;
                q.x = (unsigned)f2bf_hw(fmaxf(c[0], 0.f) * bf2f(a.x))
                    | ((unsigned)f2bf_hw(fmaxf(c[1], 0.f) * bf2f(a.y)) << 16);
                q.y = (unsigned)f2bf_hw(fmaxf(c[2], 0.f) * bf2f(a.z))
                    | ((unsigned)f2bf_hw(fmaxf(c[3], 0.f) * bf2f(a.w)) << 16);
                *(uint2*)(&s_a[nl][ml]) = q;
            }
    };

    auto conv = [&](int buf) {
#pragma unroll
        for (int ks = 0; ks < 2; ++ks) {
            short8 bfrag[2];
#pragma unroll
            for (int fb = 0; fb < 2; ++fb) {
                const int frow = cf * 32 + fb * 16 + ln;
                bfrag[fb] = *(const short8*)(
                    &s_sup[buf][frow * 64 + ((ks * 4 + kb) ^ (frow & 7)) * 8]);
            }
#pragma unroll
            for (int nt2 = 0; nt2 < 4; ++nt2) {
                short8 af = *(const short8*)(&s_a[nt2 * 16 + ln][ks * 32 + kb * 8]);
#pragma unroll
                for (int fb = 0; fb < 2; ++fb)
                    acc[nt2][fb] = __builtin_amdgcn_mfma_f32_16x16x32_bf16(
                        af, bfrag[fb], acc[nt2][fb], 0, 0, 0);
            }
        }
    };

    auto bar_lgkm = []() {
        asm volatile("s_waitcnt lgkmcnt(0)" ::: "memory");
        __builtin_amdgcn_s_barrier();
    };
    auto bar_vm0 = []() {
        asm volatile("s_waitcnt vmcnt(0) lgkmcnt(0)" ::: "memory");
        __builtin_amdgcn_s_barrier();
    };

    ushort4 avA[2][2], avB[2][2];

    stage(0, 0);
    loadAdj(0, avA);
    bar_vm0();

    for (int tt = 0; tt < 16; tt += 2) {
        stage(1, (tt + 1) * 64);
        loadAdj((tt + 1) * 64, avB);
        score(0, avA);
        bar_lgkm();
        conv(0);
        bar_vm0();

        if (tt + 2 < 16) {
            stage(0, (tt + 2) * 64);
            loadAdj((tt + 2) * 64, avA);
        }
        score(1, avB);
        bar_lgkm();
        conv(1);
        bar_vm0();
    }

#pragma unroll
    for (int nt2 = 0; nt2 < 4; ++nt2)
#pragma unroll
    for (int fb = 0; fb < 2; ++fb) {
        const int f = cf * 32 + fb * 16 + ln;
        const float bi = bias[f];
#pragma unroll
        for (int ii = 0; ii < 4; ++ii) {
            const int n = n0 + nt2 * 16 + kb * 4 + ii;
            const size_t o = ((size_t)b * N_ + n) * F_ + f;
            out[o] = fmaxf(acc[nt2][fb][ii] + bi + bf2f(resid[o]), 0.f);
        }
    }
}

// ---------------------------------------------------------------------------
extern "C" void kernel_launch(void* const* d_in, const int* in_sizes, int n_in,
                              void* d_out, int out_size, void* d_ws, size_t ws_size,
                              hipStream_t stream) {
    const float* input_features = (const float*)d_in[0];
    const int*   cycle_indices  = (const int*)  d_in[1];
    const float* weight         = (const float*)d_in[2];
    const float* bias           = (const float*)d_in[3];
    const float* src_emb        = (const float*)d_in[4];
    const float* tgt_emb        = (const float*)d_in[5];
    const float* env_W          = (const float*)d_in[6];
    const float* env_b          = (const float*)d_in[7];
    const float* res_W          = (const float*)d_in[8];
    const float* res_b          = (const float*)d_in[9];
    const float* static_adj     = (const float*)d_in[10];
    const float* env_features   = (const float*)d_in[11];
    float* out = (float*)d_out;

    // workspace layout (~33.6 MiB)
    char* wsb = (char*)d_ws;
    unsigned short* src_bf = (unsigned short*)wsb;               // 3145728 B
    unsigned short* tgt_bf = src_bf + (size_t)NPER * N_ * H_;    // 3145728 B
    unsigned short* Wt     = tgt_bf + (size_t)NPER * N_ * H_;    // 32768 B
    unsigned short* rWt    = Wt + 16384;                         // 32768 B
    unsigned short* supT   = rWt + 16384;                        // 8388608 B
    unsigned short* resid  = supT + (size_t)B_ * F_ * N_;        // 8388608 B
    unsigned short* adj_bf = resid + (size_t)B_ * N_ * F_;       // 2097152 B
    unsigned short* x_bf   = adj_bf + (size_t)N_ * N_;           // 8388608 B

    prep_all<<<6784, 256, 0, stream>>>(
        src_emb, tgt_emb, env_features, env_W, env_b,
        static_adj, weight, res_W, input_features,
        src_bf, tgt_bf, adj_bf, Wt, rWt, x_bf);

    gemm2_mfma<<<(B_ * N_) / 64, 256, 0, stream>>>(
        x_bf, Wt, rWt, res_b, supT, resid);

    conv_mfma<<<512, 256, 0, stream>>>(
        src_bf, tgt_bf, adj_bf, supT, resid, bias, cycle_indices, out);
}